// Round 3
// baseline (1428.413 us; speedup 1.0000x reference)
//
#include <hip/hip_runtime.h>
#include <hip/hip_bf16.h>
#include <cstdint>
#include <cstddef>

#define B_TOK 8192
#define DIM   1024
#define HID   4096
#define NEXP  8
#define MAXSLOT 18432  // B_TOK*2 + NEXP*255 padding (256-aligned expert offsets)

typedef __bf16 bf16x8 __attribute__((ext_vector_type(8)));
typedef float  f32x4  __attribute__((ext_vector_type(4)));

__device__ __forceinline__ void load_lds16(const void* g, void* l) {
  __builtin_amdgcn_global_load_lds(
      (const __attribute__((address_space(1))) void*)g,
      (__attribute__((address_space(3))) void*)l, 16, 0, 0);
}

// fp32 -> bf16 RNE
__device__ __forceinline__ uint16_t f2b(float f) {
  uint32_t u = __builtin_bit_cast(uint32_t, f);
  return (uint16_t)((u + 0x7FFFu + ((u >> 16) & 1u)) >> 16);
}
__device__ __forceinline__ float b2f(uint32_t hbits) {
  uint32_t u = hbits << 16;
  return __builtin_bit_cast(float, u);
}

// ---------------- init ----------------
__global__ void init_kernel(int* __restrict__ rows16k, int* __restrict__ counts,
                            int* __restrict__ cursor, float* __restrict__ zeropad) {
  int i = blockIdx.x * 256 + threadIdx.x;
  if (i < MAXSLOT) rows16k[i] = -1;
  if (i < NEXP) { counts[i] = 0; cursor[i] = 0; }
  if (i < 16) zeropad[i] = 0.f;
}

// ---------------- conversions ----------------
__global__ void convert_x_kernel(const float* __restrict__ x, uint16_t* __restrict__ xb) {
  size_t i = ((size_t)blockIdx.x * 256 + threadIdx.x) * 4;
  float4 v = *(const float4*)(x + i);
  uint64_t p = (uint64_t)f2b(v.x) | ((uint64_t)f2b(v.y) << 16) |
               ((uint64_t)f2b(v.z) << 32) | ((uint64_t)f2b(v.w) << 48);
  *(uint64_t*)(xb + i) = p;
}

// out[n][m] = bf16(in[m][n]); per-expert slab. grid(N/32, M/32, E), block(32,8)
__global__ void transpose_cvt_kernel(const float* __restrict__ in, uint16_t* __restrict__ out,
                                     int M, int N) {
  __shared__ float tile[32][33];
  const size_t base = (size_t)blockIdx.z * M * N;
  const int x0 = blockIdx.x * 32, y0 = blockIdx.y * 32;
  const int tx = threadIdx.x, ty = threadIdx.y;
#pragma unroll
  for (int i = 0; i < 4; i++)
    tile[ty + i * 8][tx] = in[base + (size_t)(y0 + ty + i * 8) * N + x0 + tx];
  __syncthreads();
#pragma unroll
  for (int i = 0; i < 4; i++)
    out[base + (size_t)(x0 + ty + i * 8) * M + y0 + tx] = f2b(tile[tx][ty + i * 8]);
}

// ---------------- router ----------------
__global__ void router_kernel(const float* __restrict__ x, const float* __restrict__ Wr,
                              const float* __restrict__ br, int* __restrict__ top_i,
                              float* __restrict__ top_w, int* __restrict__ counts) {
  const int wave = threadIdx.x >> 6, lane = threadIdx.x & 63;
  const int b = blockIdx.x * 4 + wave;
  float acc[NEXP];
#pragma unroll
  for (int e = 0; e < NEXP; e++) acc[e] = 0.f;
  const float* xr = x + (size_t)b * DIM;
  for (int d = lane; d < DIM; d += 64) {
    float xv = xr[d];
    const float4* wr = (const float4*)(Wr + (size_t)d * NEXP);
    float4 w0 = wr[0], w1 = wr[1];
    acc[0] += xv * w0.x; acc[1] += xv * w0.y; acc[2] += xv * w0.z; acc[3] += xv * w0.w;
    acc[4] += xv * w1.x; acc[5] += xv * w1.y; acc[6] += xv * w1.z; acc[7] += xv * w1.w;
  }
#pragma unroll
  for (int e = 0; e < NEXP; e++)
#pragma unroll
    for (int off = 32; off; off >>= 1) acc[e] += __shfl_xor(acc[e], off);
  if (lane == 0) {
    float l[NEXP];
#pragma unroll
    for (int e = 0; e < NEXP; e++) l[e] = acc[e] + br[e];
    int i0 = 0; float v0 = l[0];
#pragma unroll
    for (int e = 1; e < NEXP; e++) if (l[e] > v0) { v0 = l[e]; i0 = e; }
    int i1 = -1; float v1 = -3.4e38f;
#pragma unroll
    for (int e = 0; e < NEXP; e++) if (e != i0 && l[e] > v1) { v1 = l[e]; i1 = e; }
    float w0 = 1.f / (1.f + expf(v1 - v0));
    float w1 = 1.f - w0;
    top_i[b * 2 + 0] = i0; top_i[b * 2 + 1] = i1;
    top_w[b * 2 + 0] = w0; top_w[b * 2 + 1] = w1;
    atomicAdd(&counts[i0], 1);
    atomicAdd(&counts[i1], 1);
  }
}

__global__ void offsets_kernel(const int* __restrict__ counts, int* __restrict__ off_p) {
  int o = 0;
  for (int e = 0; e < NEXP; e++) { off_p[e] = o; o += (counts[e] + 255) & ~255; }
  off_p[NEXP] = o;
}

__global__ void scatter_kernel(const int* __restrict__ top_i, const float* __restrict__ top_w,
                               const int* __restrict__ off_p, int* __restrict__ cursor,
                               int* __restrict__ rows16k, float* __restrict__ wgt,
                               int* __restrict__ slot_of) {
  int b = blockIdx.x * 256 + threadIdx.x;
  if (b >= B_TOK) return;
#pragma unroll
  for (int k = 0; k < 2; k++) {
    int e = top_i[b * 2 + k];
    int pos = off_p[e] + atomicAdd(&cursor[e], 1);
    rows16k[pos] = b;
    wgt[pos] = top_w[b * 2 + k];
    slot_of[b * 2 + k] = pos;
  }
}

// ---------------- 256x256 BK=64 deep-pipelined grouped GEMM ----------------
// 512 threads = 8 waves as 2(M)x4(N); per-wave output 128x64.
// Double-buffered LDS (2 x (A 32KB + B 32KB) = 128KB), raw s_barrier + counted vmcnt(8).
// XOR chunk swizzle (chunk ^= row&7) pre-applied on global source, applied on ds_read.
template<bool GATHER, bool GELU>
__global__ __launch_bounds__(512, 2) void gemm256_kernel(
    const uint16_t* __restrict__ Abase, const uint16_t* __restrict__ Wb,
    const float* __restrict__ bias, const int* __restrict__ rows16k,
    const int* __restrict__ counts, const int* __restrict__ off_p,
    const float* __restrict__ zeropad, uint16_t* __restrict__ outb,
    int Nfull, int Kdim) {
  const int e = blockIdx.z;
  const int ne = counts[e];
  const int rb = blockIdx.x;
  if (rb * 256 >= ne) return;
  const int nbase = blockIdx.y * 256;
  const int sbase = off_p[e] + rb * 256;
  const int nt = Kdim / 64;

  __shared__ __align__(16) uint16_t smem[2 * 2 * 256 * 64];  // 128 KiB

  const int tid = threadIdx.x;
  const int lane = tid & 63;
  const int wid = tid >> 6;
  const int wm = wid >> 2, wn = wid & 3;
  const int lr = lane & 15, lh = lane >> 4;
  const int swz8 = (((tid & 7) ^ ((tid >> 3) & 7)) * 8);

  const uint16_t* srcA[4]; int stA[4];
  const uint16_t* srcB[4];
#pragma unroll
  for (int is = 0; is < 4; is++) {
    const int r = (tid >> 3) + is * 64;
    if (GATHER) {
      int tok = rows16k[sbase + r];
      srcA[is] = (tok >= 0) ? (Abase + (size_t)tok * Kdim + swz8) : (const uint16_t*)zeropad;
      stA[is] = (tok >= 0) ? 64 : 0;
    } else {
      srcA[is] = Abase + (size_t)(sbase + r) * Kdim + swz8;
      stA[is] = 64;
    }
    srcB[is] = Wb + ((size_t)e * Nfull + nbase + r) * Kdim + swz8;
  }

  f32x4 acc[8][4];
#pragma unroll
  for (int mi = 0; mi < 8; mi++)
#pragma unroll
    for (int ni = 0; ni < 4; ni++) acc[mi][ni] = (f32x4){0.f, 0.f, 0.f, 0.f};

  auto STAGE = [&](int buf) {
    uint16_t* dA = &smem[buf * 32768];
    uint16_t* dB = dA + 16384;
#pragma unroll
    for (int is = 0; is < 4; is++) {
      load_lds16(srcA[is], dA + (is * 512 + tid) * 8);
      load_lds16(srcB[is], dB + (is * 512 + tid) * 8);
      srcA[is] += stA[is]; srcB[is] += 64;
    }
  };

  STAGE(0);  // prologue: tile 0 in flight (8 loads)

  for (int t = 0; t < nt; ++t) {
    const int cur = t & 1;
    if (t + 1 < nt) {
      STAGE(cur ^ 1);  // issue next tile: 16 outstanding
      asm volatile("s_waitcnt vmcnt(8)" ::: "memory");   // tile t landed; next 8 in flight
    } else {
      asm volatile("s_waitcnt vmcnt(0)" ::: "memory");
    }
    __builtin_amdgcn_s_barrier();   // all waves: tile t fully in LDS

    const uint16_t* sA = &smem[cur * 32768];
    const uint16_t* sB = sA + 16384;

    bf16x8 bfr[2][4];
#pragma unroll
    for (int kk = 0; kk < 2; kk++)
#pragma unroll
      for (int ni = 0; ni < 4; ni++) {
        const int row = wn * 64 + ni * 16 + lr;
        const int c = (kk * 4 + lh) ^ (lr & 7);
        bfr[kk][ni] = *(const bf16x8*)&sB[row * 64 + c * 8];
      }
    __builtin_amdgcn_s_setprio(1);
#pragma unroll
    for (int kk = 0; kk < 2; kk++) {
      bf16x8 afr[8];
#pragma unroll
      for (int mi = 0; mi < 8; mi++) {
        const int row = wm * 128 + mi * 16 + lr;
        const int c = (kk * 4 + lh) ^ (lr & 7);
        afr[mi] = *(const bf16x8*)&sA[row * 64 + c * 8];
      }
#pragma unroll
      for (int mi = 0; mi < 8; mi++)
#pragma unroll
        for (int ni = 0; ni < 4; ni++)
          acc[mi][ni] = __builtin_amdgcn_mfma_f32_16x16x32_bf16(afr[mi], bfr[kk][ni], acc[mi][ni], 0, 0, 0);
    }
    __builtin_amdgcn_s_setprio(0);
    __builtin_amdgcn_s_barrier();   // all reads of buf[cur] done -> next iter may overwrite
  }

  float biasv[4];
#pragma unroll
  for (int ni = 0; ni < 4; ni++)
    biasv[ni] = bias[(size_t)e * Nfull + nbase + wn * 64 + ni * 16 + lr];
#pragma unroll
  for (int mi = 0; mi < 8; mi++)
#pragma unroll
    for (int ni = 0; ni < 4; ni++)
#pragma unroll
      for (int r = 0; r < 4; r++) {
        const int row = wm * 128 + mi * 16 + lh * 4 + r;
        const int col = nbase + wn * 64 + ni * 16 + lr;
        float t = acc[mi][ni][r] + biasv[ni];
        float g;
        if (GELU) {
          // tanh-form GELU via exp2: g = t * e/(e+1), e = 2^(t*(c1 + c2*t^2))
          float t2 = t * t;
          float v = t * fmaf(0.1029437f, t2, 2.3022085f);
#if __has_builtin(__builtin_amdgcn_exp2f)
          float ex = __builtin_amdgcn_exp2f(v);
#else
          float ex = exp2f(v);
#endif
#if __has_builtin(__builtin_amdgcn_rcpf)
          float rr = __builtin_amdgcn_rcpf(ex + 1.0f);
#else
          float rr = 1.0f / (ex + 1.0f);
#endif
          g = t - t * rr;
        } else {
          g = t;
        }
        outb[(size_t)(sbase + row) * Nfull + col] = f2b(g);
      }
}

// ---------------- combine: out[b] = w0*y[slot0] + w1*y[slot1] ----------------
__global__ void combine_kernel(const uint16_t* __restrict__ y, const int* __restrict__ slot_of,
                               const float* __restrict__ top_w, float* __restrict__ out) {
  const int b = blockIdx.x;
  const int t = threadIdx.x;
  const int s0 = slot_of[b * 2], s1 = slot_of[b * 2 + 1];
  const float w0 = top_w[b * 2], w1 = top_w[b * 2 + 1];
  uint64_t p0 = *(const uint64_t*)(y + (size_t)s0 * DIM + t * 4);
  uint64_t p1 = *(const uint64_t*)(y + (size_t)s1 * DIM + t * 4);
  float4 r;
  r.x = w0 * b2f((uint32_t)(p0 >> 0) & 0xFFFFu)  + w1 * b2f((uint32_t)(p1 >> 0) & 0xFFFFu);
  r.y = w0 * b2f((uint32_t)(p0 >> 16) & 0xFFFFu) + w1 * b2f((uint32_t)(p1 >> 16) & 0xFFFFu);
  r.z = w0 * b2f((uint32_t)(p0 >> 32) & 0xFFFFu) + w1 * b2f((uint32_t)(p1 >> 32) & 0xFFFFu);
  r.w = w0 * b2f((uint32_t)(p0 >> 48) & 0xFFFFu) + w1 * b2f((uint32_t)(p1 >> 48) & 0xFFFFu);
  *(float4*)(out + (size_t)b * DIM + t * 4) = r;
}

// ---------------- launch ----------------
extern "C" void kernel_launch(void* const* d_in, const int* in_sizes, int n_in,
                              void* d_out, int out_size, void* d_ws, size_t ws_size,
                              hipStream_t stream) {
  const float* x  = (const float*)d_in[0];
  const float* Wr = (const float*)d_in[1];
  const float* br = (const float*)d_in[2];
  const float* W1 = (const float*)d_in[3];
  const float* b1 = (const float*)d_in[4];
  const float* W2 = (const float*)d_in[5];
  const float* b2 = (const float*)d_in[6];
  float* out = (float*)d_out;

  char* ws = (char*)d_ws;
  uint16_t* W1b = (uint16_t*)ws; ws += (size_t)NEXP * HID * DIM * 2;   // 64 MB
  uint16_t* W2b = (uint16_t*)ws; ws += (size_t)NEXP * DIM * HID * 2;   // 64 MB
  uint16_t* xb  = (uint16_t*)ws; ws += (size_t)B_TOK * DIM * 2;        // 16 MB
  uint16_t* h   = (uint16_t*)ws; ws += (size_t)MAXSLOT * HID * 2;      // 151 MB
  uint16_t* yb  = (uint16_t*)ws; ws += (size_t)MAXSLOT * DIM * 2;      // 38 MB
  int*   top_i  = (int*)ws;   ws += (size_t)B_TOK * 2 * 4;
  float* top_w  = (float*)ws; ws += (size_t)B_TOK * 2 * 4;
  int*   slot_of= (int*)ws;   ws += (size_t)B_TOK * 2 * 4;
  int*   rows16k= (int*)ws;   ws += (size_t)MAXSLOT * 4;
  float* wgt    = (float*)ws; ws += (size_t)MAXSLOT * 4;
  int*   counts = (int*)ws;   ws += 64;
  int*   cursor = (int*)ws;   ws += 64;
  int*   off_p  = (int*)ws;   ws += 64;
  float* zeropad= (float*)ws; ws += 64;

  init_kernel<<<dim3((MAXSLOT + 255) / 256), dim3(256), 0, stream>>>(rows16k, counts, cursor, zeropad);
  convert_x_kernel<<<dim3((B_TOK * DIM / 4) / 256), dim3(256), 0, stream>>>(x, xb);
  transpose_cvt_kernel<<<dim3(HID / 32, DIM / 32, NEXP), dim3(32, 8), 0, stream>>>(W1, W1b, DIM, HID);
  transpose_cvt_kernel<<<dim3(DIM / 32, HID / 32, NEXP), dim3(32, 8), 0, stream>>>(W2, W2b, HID, DIM);
  router_kernel<<<dim3(B_TOK / 4), dim3(256), 0, stream>>>(x, Wr, br, top_i, top_w, counts);
  offsets_kernel<<<dim3(1), dim3(1), 0, stream>>>(counts, off_p);
  scatter_kernel<<<dim3(B_TOK / 256), dim3(256), 0, stream>>>(top_i, top_w, off_p, cursor, rows16k, wgt, slot_of);
  // gemm1: h = gelu(gather(x) @ W1^T + b1)   [M=slots, N=HID, K=DIM]
  gemm256_kernel<true, true><<<dim3(32, HID / 256, NEXP), dim3(512), 0, stream>>>(
      xb, W1b, b1, rows16k, counts, off_p, zeropad, h, HID, DIM);
  // gemm2: y = h @ W2^T + b2                  [M=slots, N=DIM, K=HID]
  gemm256_kernel<false, false><<<dim3(32, DIM / 256, NEXP), dim3(512), 0, stream>>>(
      h, W2b, b2, rows16k, counts, off_p, zeropad, yb, DIM, HID);
  combine_kernel<<<dim3(B_TOK), dim3(256), 0, stream>>>(yb, slot_of, top_w, out);
}

// Round 4
// 786.284 us; speedup vs baseline: 1.8167x; 1.8167x over previous
//
#include <hip/hip_runtime.h>
#include <hip/hip_bf16.h>
#include <cstdint>
#include <cstddef>

#define B_TOK 8192
#define DIM   1024
#define HID   4096
#define NEXP  8
#define MAXSLOT 18432  // B_TOK*2 + NEXP*255 padding (256-aligned expert offsets)

typedef __bf16 bf16x8 __attribute__((ext_vector_type(8)));
typedef float  f32x4  __attribute__((ext_vector_type(4)));

__device__ __forceinline__ void load_lds16(const void* g, void* l) {
  __builtin_amdgcn_global_load_lds(
      (const __attribute__((address_space(1))) void*)g,
      (__attribute__((address_space(3))) void*)l, 16, 0, 0);
}

// fp32 -> bf16 RNE
__device__ __forceinline__ uint16_t f2b(float f) {
  uint32_t u = __builtin_bit_cast(uint32_t, f);
  return (uint16_t)((u + 0x7FFFu + ((u >> 16) & 1u)) >> 16);
}
__device__ __forceinline__ float b2f(uint32_t hbits) {
  uint32_t u = hbits << 16;
  return __builtin_bit_cast(float, u);
}

// ---------------- init ----------------
__global__ void init_kernel(int* __restrict__ rows16k, int* __restrict__ counts,
                            int* __restrict__ cursor, float* __restrict__ zeropad) {
  int i = blockIdx.x * 256 + threadIdx.x;
  if (i < MAXSLOT) rows16k[i] = -1;
  if (i < NEXP) { counts[i] = 0; cursor[i] = 0; }
  if (i < 16) zeropad[i] = 0.f;
}

// ---------------- conversions ----------------
__global__ void convert_x_kernel(const float* __restrict__ x, uint16_t* __restrict__ xb) {
  size_t i = ((size_t)blockIdx.x * 256 + threadIdx.x) * 4;
  float4 v = *(const float4*)(x + i);
  uint64_t p = (uint64_t)f2b(v.x) | ((uint64_t)f2b(v.y) << 16) |
               ((uint64_t)f2b(v.z) << 32) | ((uint64_t)f2b(v.w) << 48);
  *(uint64_t*)(xb + i) = p;
}

// out[n][m] = bf16(in[m][n]); per-expert slab. grid(N/32, M/32, E), block(32,8)
__global__ void transpose_cvt_kernel(const float* __restrict__ in, uint16_t* __restrict__ out,
                                     int M, int N) {
  __shared__ float tile[32][33];
  const size_t base = (size_t)blockIdx.z * M * N;
  const int x0 = blockIdx.x * 32, y0 = blockIdx.y * 32;
  const int tx = threadIdx.x, ty = threadIdx.y;
#pragma unroll
  for (int i = 0; i < 4; i++)
    tile[ty + i * 8][tx] = in[base + (size_t)(y0 + ty + i * 8) * N + x0 + tx];
  __syncthreads();
  const int tl = ty * 32 + tx;
  const int r = tl >> 3, c4 = (tl & 7) * 4;
  uint64_t p = (uint64_t)f2b(tile[c4 + 0][r]) | ((uint64_t)f2b(tile[c4 + 1][r]) << 16) |
               ((uint64_t)f2b(tile[c4 + 2][r]) << 32) | ((uint64_t)f2b(tile[c4 + 3][r]) << 48);
  *(uint64_t*)(out + base + (size_t)(x0 + r) * M + y0 + c4) = p;
}

// ---------------- router ----------------
__global__ void router_kernel(const float* __restrict__ x, const float* __restrict__ Wr,
                              const float* __restrict__ br, int* __restrict__ top_i,
                              float* __restrict__ top_w, int* __restrict__ counts) {
  const int wave = threadIdx.x >> 6, lane = threadIdx.x & 63;
  const int b = blockIdx.x * 4 + wave;
  float acc[NEXP];
#pragma unroll
  for (int e = 0; e < NEXP; e++) acc[e] = 0.f;
  const float* xr = x + (size_t)b * DIM;
  for (int d = lane; d < DIM; d += 64) {
    float xv = xr[d];
    const float4* wr = (const float4*)(Wr + (size_t)d * NEXP);
    float4 w0 = wr[0], w1 = wr[1];
    acc[0] += xv * w0.x; acc[1] += xv * w0.y; acc[2] += xv * w0.z; acc[3] += xv * w0.w;
    acc[4] += xv * w1.x; acc[5] += xv * w1.y; acc[6] += xv * w1.z; acc[7] += xv * w1.w;
  }
#pragma unroll
  for (int e = 0; e < NEXP; e++)
#pragma unroll
    for (int off = 32; off; off >>= 1) acc[e] += __shfl_xor(acc[e], off);
  if (lane == 0) {
    float l[NEXP];
#pragma unroll
    for (int e = 0; e < NEXP; e++) l[e] = acc[e] + br[e];
    int i0 = 0; float v0 = l[0];
#pragma unroll
    for (int e = 1; e < NEXP; e++) if (l[e] > v0) { v0 = l[e]; i0 = e; }
    int i1 = -1; float v1 = -3.4e38f;
#pragma unroll
    for (int e = 0; e < NEXP; e++) if (e != i0 && l[e] > v1) { v1 = l[e]; i1 = e; }
    float w0 = 1.f / (1.f + expf(v1 - v0));
    float w1 = 1.f - w0;
    top_i[b * 2 + 0] = i0; top_i[b * 2 + 1] = i1;
    top_w[b * 2 + 0] = w0; top_w[b * 2 + 1] = w1;
    atomicAdd(&counts[i0], 1);
    atomicAdd(&counts[i1], 1);
  }
}

__global__ void offsets_kernel(const int* __restrict__ counts, int* __restrict__ off_p) {
  int o = 0;
  for (int e = 0; e < NEXP; e++) { off_p[e] = o; o += (counts[e] + 255) & ~255; }
  off_p[NEXP] = o;
}

__global__ void scatter_kernel(const int* __restrict__ top_i, const float* __restrict__ top_w,
                               const int* __restrict__ off_p, int* __restrict__ cursor,
                               int* __restrict__ rows16k, float* __restrict__ wgt,
                               int* __restrict__ slot_of) {
  int b = blockIdx.x * 256 + threadIdx.x;
  if (b >= B_TOK) return;
#pragma unroll
  for (int k = 0; k < 2; k++) {
    int e = top_i[b * 2 + k];
    int pos = off_p[e] + atomicAdd(&cursor[e], 1);
    rows16k[pos] = b;
    wgt[pos] = top_w[b * 2 + k];
    slot_of[b * 2 + k] = pos;
  }
}

// ---------------- 256x256 BK=64 2-phase grouped GEMM (m230-V0 template) ----------------
// 512 threads = 8 waves as 2(M)x4(N); per-wave output 128x64.
// Double-buffered LDS (128 KiB). Per K-step: STAGE(next) -> COMPUTE(cur) -> __syncthreads().
// The syncthreads drain lands AFTER ~2500cy of MFMA, hiding the prefetch latency.
// XOR chunk swizzle (chunk ^= row&7) pre-applied on global source, applied on ds_read.
template<bool GATHER, bool GELU>
__global__ __launch_bounds__(512, 2) void gemm256_kernel(
    const uint16_t* __restrict__ Abase, const uint16_t* __restrict__ Wb,
    const float* __restrict__ bias, const int* __restrict__ rows16k,
    const int* __restrict__ counts, const int* __restrict__ off_p,
    const float* __restrict__ zeropad, uint16_t* __restrict__ outb,
    int Nfull, int Kdim) {
  const int e = blockIdx.z;
  const int ne = counts[e];
  const int rb = blockIdx.y;
  if (rb * 256 >= ne) return;
  const int nbase = blockIdx.x * 256;
  const int sbase = off_p[e] + rb * 256;
  const int nt = Kdim / 64;

  __shared__ __align__(16) uint16_t smem[2 * 2 * 256 * 64];  // 128 KiB

  const int tid = threadIdx.x;
  const int lane = tid & 63;
  const int wid = tid >> 6;
  const int wm = wid >> 2, wn = wid & 3;
  const int lr = lane & 15, lh = lane >> 4;
  const int swz8 = (((tid & 7) ^ ((tid >> 3) & 7)) * 8);

  const uint16_t* srcA[4]; int stA[4];
  const uint16_t* srcB[4];
#pragma unroll
  for (int is = 0; is < 4; is++) {
    const int r = (tid >> 3) + is * 64;
    if (GATHER) {
      int tok = rows16k[sbase + r];
      srcA[is] = (tok >= 0) ? (Abase + (size_t)tok * Kdim + swz8) : (const uint16_t*)zeropad;
      stA[is] = (tok >= 0) ? 64 : 0;
    } else {
      srcA[is] = Abase + (size_t)(sbase + r) * Kdim + swz8;
      stA[is] = 64;
    }
    srcB[is] = Wb + ((size_t)e * Nfull + nbase + r) * Kdim + swz8;
  }

  f32x4 acc[8][4];
#pragma unroll
  for (int mi = 0; mi < 8; mi++)
#pragma unroll
    for (int ni = 0; ni < 4; ni++) acc[mi][ni] = (f32x4){0.f, 0.f, 0.f, 0.f};

  auto STAGE = [&](int buf) {
    uint16_t* dA = &smem[buf * 32768];
    uint16_t* dB = dA + 16384;
#pragma unroll
    for (int is = 0; is < 4; is++) {
      load_lds16(srcA[is], dA + (is * 512 + tid) * 8);
      load_lds16(srcB[is], dB + (is * 512 + tid) * 8);
      srcA[is] += stA[is]; srcB[is] += 64;
    }
  };

  auto COMPUTE = [&](int buf) {
    const uint16_t* sA = &smem[buf * 32768];
    const uint16_t* sB = sA + 16384;
    bf16x8 bfr[2][4];
#pragma unroll
    for (int kk = 0; kk < 2; kk++)
#pragma unroll
      for (int ni = 0; ni < 4; ni++) {
        const int row = wn * 64 + ni * 16 + lr;
        const int c = (kk * 4 + lh) ^ (lr & 7);
        bfr[kk][ni] = *(const bf16x8*)&sB[row * 64 + c * 8];
      }
#pragma unroll
    for (int kk = 0; kk < 2; kk++) {
      bf16x8 afr[8];
#pragma unroll
      for (int mi = 0; mi < 8; mi++) {
        const int row = wm * 128 + mi * 16 + lr;
        const int c = (kk * 4 + lh) ^ (lr & 7);
        afr[mi] = *(const bf16x8*)&sA[row * 64 + c * 8];
      }
#pragma unroll
      for (int mi = 0; mi < 8; mi++)
#pragma unroll
        for (int ni = 0; ni < 4; ni++)
          acc[mi][ni] = __builtin_amdgcn_mfma_f32_16x16x32_bf16(afr[mi], bfr[kk][ni], acc[mi][ni], 0, 0, 0);
    }
  };

  STAGE(0);
  __syncthreads();                 // buf0 staged (drain lands immediately after issue; prologue only)
  for (int t = 0; t < nt - 1; ++t) {
    STAGE((t & 1) ^ 1);            // issue next tile FIRST
    COMPUTE(t & 1);                // ~2500cy MFMA hides the prefetch latency
    __syncthreads();               // single drain+barrier per K-step
  }
  COMPUTE((nt - 1) & 1);

  float biasv[4];
#pragma unroll
  for (int ni = 0; ni < 4; ni++)
    biasv[ni] = bias[(size_t)e * Nfull + nbase + wn * 64 + ni * 16 + lr];
#pragma unroll
  for (int mi = 0; mi < 8; mi++)
#pragma unroll
    for (int ni = 0; ni < 4; ni++)
#pragma unroll
      for (int r = 0; r < 4; r++) {
        const int row = wm * 128 + mi * 16 + lh * 4 + r;
        const int col = nbase + wn * 64 + ni * 16 + lr;
        float t = acc[mi][ni][r] + biasv[ni];
        float g;
        if (GELU) {
          // tanh-form GELU via exp2: g = t - t/(2^(t*(c1 + c2*t^2)) + 1)
          float t2 = t * t;
          float v = t * fmaf(0.1029437f, t2, 2.3022085f);
          float ex = exp2f(v);
          float rr = 1.0f / (ex + 1.0f);
          g = t - t * rr;
        } else {
          g = t;
        }
        outb[(size_t)(sbase + row) * Nfull + col] = f2b(g);
      }
}

// ---------------- combine: out[b] = w0*y[slot0] + w1*y[slot1] ----------------
__global__ void combine_kernel(const uint16_t* __restrict__ y, const int* __restrict__ slot_of,
                               const float* __restrict__ top_w, float* __restrict__ out) {
  const int b = blockIdx.x;
  const int t = threadIdx.x;
  const int s0 = slot_of[b * 2], s1 = slot_of[b * 2 + 1];
  const float w0 = top_w[b * 2], w1 = top_w[b * 2 + 1];
  uint64_t p0 = *(const uint64_t*)(y + (size_t)s0 * DIM + t * 4);
  uint64_t p1 = *(const uint64_t*)(y + (size_t)s1 * DIM + t * 4);
  float4 r;
  r.x = w0 * b2f((uint32_t)(p0 >> 0) & 0xFFFFu)  + w1 * b2f((uint32_t)(p1 >> 0) & 0xFFFFu);
  r.y = w0 * b2f((uint32_t)(p0 >> 16) & 0xFFFFu) + w1 * b2f((uint32_t)(p1 >> 16) & 0xFFFFu);
  r.z = w0 * b2f((uint32_t)(p0 >> 32) & 0xFFFFu) + w1 * b2f((uint32_t)(p1 >> 32) & 0xFFFFu);
  r.w = w0 * b2f((uint32_t)(p0 >> 48) & 0xFFFFu) + w1 * b2f((uint32_t)(p1 >> 48) & 0xFFFFu);
  *(float4*)(out + (size_t)b * DIM + t * 4) = r;
}

// ---------------- launch ----------------
extern "C" void kernel_launch(void* const* d_in, const int* in_sizes, int n_in,
                              void* d_out, int out_size, void* d_ws, size_t ws_size,
                              hipStream_t stream) {
  const float* x  = (const float*)d_in[0];
  const float* Wr = (const float*)d_in[1];
  const float* br = (const float*)d_in[2];
  const float* W1 = (const float*)d_in[3];
  const float* b1 = (const float*)d_in[4];
  const float* W2 = (const float*)d_in[5];
  const float* b2 = (const float*)d_in[6];
  float* out = (float*)d_out;

  char* ws = (char*)d_ws;
  uint16_t* W1b = (uint16_t*)ws; ws += (size_t)NEXP * HID * DIM * 2;   // 64 MB
  uint16_t* W2b = (uint16_t*)ws; ws += (size_t)NEXP * DIM * HID * 2;   // 64 MB
  uint16_t* xb  = (uint16_t*)ws; ws += (size_t)B_TOK * DIM * 2;        // 16 MB
  uint16_t* h   = (uint16_t*)ws; ws += (size_t)MAXSLOT * HID * 2;      // 151 MB
  uint16_t* yb  = (uint16_t*)ws; ws += (size_t)MAXSLOT * DIM * 2;      // 38 MB
  int*   top_i  = (int*)ws;   ws += (size_t)B_TOK * 2 * 4;
  float* top_w  = (float*)ws; ws += (size_t)B_TOK * 2 * 4;
  int*   slot_of= (int*)ws;   ws += (size_t)B_TOK * 2 * 4;
  int*   rows16k= (int*)ws;   ws += (size_t)MAXSLOT * 4;
  float* wgt    = (float*)ws; ws += (size_t)MAXSLOT * 4;
  int*   counts = (int*)ws;   ws += 64;
  int*   cursor = (int*)ws;   ws += 64;
  int*   off_p  = (int*)ws;   ws += 64;
  float* zeropad= (float*)ws; ws += 64;

  init_kernel<<<dim3((MAXSLOT + 255) / 256), dim3(256), 0, stream>>>(rows16k, counts, cursor, zeropad);
  convert_x_kernel<<<dim3((B_TOK * DIM / 4) / 256), dim3(256), 0, stream>>>(x, xb);
  transpose_cvt_kernel<<<dim3(HID / 32, DIM / 32, NEXP), dim3(32, 8), 0, stream>>>(W1, W1b, DIM, HID);
  transpose_cvt_kernel<<<dim3(DIM / 32, HID / 32, NEXP), dim3(32, 8), 0, stream>>>(W2, W2b, HID, DIM);
  router_kernel<<<dim3(B_TOK / 4), dim3(256), 0, stream>>>(x, Wr, br, top_i, top_w, counts);
  offsets_kernel<<<dim3(1), dim3(1), 0, stream>>>(counts, off_p);
  scatter_kernel<<<dim3(B_TOK / 256), dim3(256), 0, stream>>>(top_i, top_w, off_p, cursor, rows16k, wgt, slot_of);
  // gemm1: h = gelu(gather(x) @ W1^T + b1)   [M=slots, N=HID, K=DIM]
  gemm256_kernel<true, true><<<dim3(HID / 256, 32, NEXP), dim3(512), 0, stream>>>(
      xb, W1b, b1, rows16k, counts, off_p, zeropad, h, HID, DIM);
  // gemm2: y = h @ W2^T + b2                  [M=slots, N=DIM, K=HID]
  gemm256_kernel<false, false><<<dim3(DIM / 256, 32, NEXP), dim3(512), 0, stream>>>(
      h, W2b, b2, rows16k, counts, off_p, zeropad, yb, DIM, HID);
  combine_kernel<<<dim3(B_TOK), dim3(256), 0, stream>>>(yb, slot_of, top_w, out);
}

// Round 6
// 784.885 us; speedup vs baseline: 1.8199x; 1.0018x over previous
//
#include <hip/hip_runtime.h>
#include <hip/hip_bf16.h>
#include <cstdint>
#include <cstddef>

#define B_TOK 8192
#define DIM   1024
#define HID   4096
#define NEXP  8
#define MAXSLOT 18432  // B_TOK*2 + NEXP*255 padding (256-aligned expert offsets)

typedef __bf16 bf16x8 __attribute__((ext_vector_type(8)));
typedef float  f32x4  __attribute__((ext_vector_type(4)));

__device__ __forceinline__ void load_lds16(const void* g, void* l) {
  __builtin_amdgcn_global_load_lds(
      (const __attribute__((address_space(1))) void*)g,
      (__attribute__((address_space(3))) void*)l, 16, 0, 0);
}

// fp32 -> bf16 RNE
__device__ __forceinline__ uint16_t f2b(float f) {
  uint32_t u = __builtin_bit_cast(uint32_t, f);
  return (uint16_t)((u + 0x7FFFu + ((u >> 16) & 1u)) >> 16);
}
__device__ __forceinline__ float b2f(uint32_t hbits) {
  uint32_t u = hbits << 16;
  return __builtin_bit_cast(float, u);
}

// ---------------- init ----------------
__global__ void init_kernel(int* __restrict__ rows16k, int* __restrict__ counts,
                            int* __restrict__ cursor, float* __restrict__ zeropad) {
  int i = blockIdx.x * 256 + threadIdx.x;
  if (i < MAXSLOT) rows16k[i] = -1;
  if (i < NEXP) { counts[i] = 0; cursor[i] = 0; }
  if (i < 16) zeropad[i] = 0.f;
}

// out[n][m] = bf16(in[m][n]); per-expert slab. grid(N/32, M/32, E), block(32,8)
__global__ void transpose_cvt_kernel(const float* __restrict__ in, uint16_t* __restrict__ out,
                                     int M, int N) {
  __shared__ float tile[32][33];
  const size_t base = (size_t)blockIdx.z * M * N;
  const int x0 = blockIdx.x * 32, y0 = blockIdx.y * 32;
  const int tx = threadIdx.x, ty = threadIdx.y;
#pragma unroll
  for (int i = 0; i < 4; i++)
    tile[ty + i * 8][tx] = in[base + (size_t)(y0 + ty + i * 8) * N + x0 + tx];
  __syncthreads();
  const int tl = ty * 32 + tx;
  const int r = tl >> 3, c4 = (tl & 7) * 4;
  uint64_t p = (uint64_t)f2b(tile[c4 + 0][r]) | ((uint64_t)f2b(tile[c4 + 1][r]) << 16) |
               ((uint64_t)f2b(tile[c4 + 2][r]) << 32) | ((uint64_t)f2b(tile[c4 + 3][r]) << 48);
  *(uint64_t*)(out + base + (size_t)(x0 + r) * M + y0 + c4) = p;
}

// ---------------- router (+ x -> bf16 conversion fused) ----------------
__global__ void router_kernel(const float* __restrict__ x, const float* __restrict__ Wr,
                              const float* __restrict__ br, int* __restrict__ top_i,
                              float* __restrict__ top_w, int* __restrict__ counts,
                              uint16_t* __restrict__ xb) {
  const int wave = threadIdx.x >> 6, lane = threadIdx.x & 63;
  const int b = blockIdx.x * 4 + wave;
  float acc[NEXP];
#pragma unroll
  for (int e = 0; e < NEXP; e++) acc[e] = 0.f;
  const float* xr = x + (size_t)b * DIM;
  uint16_t* xbr = xb + (size_t)b * DIM;
  for (int d = lane; d < DIM; d += 64) {
    float xv = xr[d];
    xbr[d] = f2b(xv);
    const float4* wr = (const float4*)(Wr + (size_t)d * NEXP);
    float4 w0 = wr[0], w1 = wr[1];
    acc[0] += xv * w0.x; acc[1] += xv * w0.y; acc[2] += xv * w0.z; acc[3] += xv * w0.w;
    acc[4] += xv * w1.x; acc[5] += xv * w1.y; acc[6] += xv * w1.z; acc[7] += xv * w1.w;
  }
#pragma unroll
  for (int e = 0; e < NEXP; e++)
#pragma unroll
    for (int off = 32; off; off >>= 1) acc[e] += __shfl_xor(acc[e], off);
  if (lane == 0) {
    float l[NEXP];
#pragma unroll
    for (int e = 0; e < NEXP; e++) l[e] = acc[e] + br[e];
    int i0 = 0; float v0 = l[0];
#pragma unroll
    for (int e = 1; e < NEXP; e++) if (l[e] > v0) { v0 = l[e]; i0 = e; }
    int i1 = -1; float v1 = -3.4e38f;
#pragma unroll
    for (int e = 0; e < NEXP; e++) if (e != i0 && l[e] > v1) { v1 = l[e]; i1 = e; }
    float w0 = 1.f / (1.f + expf(v1 - v0));
    float w1 = 1.f - w0;
    top_i[b * 2 + 0] = i0; top_i[b * 2 + 1] = i1;
    top_w[b * 2 + 0] = w0; top_w[b * 2 + 1] = w1;
    atomicAdd(&counts[i0], 1);
    atomicAdd(&counts[i1], 1);
  }
}

__global__ void offsets_kernel(const int* __restrict__ counts, int* __restrict__ off_p) {
  int o = 0;
  for (int e = 0; e < NEXP; e++) { off_p[e] = o; o += (counts[e] + 255) & ~255; }
  off_p[NEXP] = o;
}

// wave-aggregated scatter: 8 atomics per wave per k instead of 64
__global__ void scatter_kernel(const int* __restrict__ top_i, const float* __restrict__ top_w,
                               const int* __restrict__ off_p, int* __restrict__ cursor,
                               int* __restrict__ rows16k, float* __restrict__ wgt,
                               int* __restrict__ slot_of) {
  const int b = blockIdx.x * 256 + threadIdx.x;
  const int lane = threadIdx.x & 63;
#pragma unroll
  for (int k = 0; k < 2; k++) {
    const int e = top_i[b * 2 + k];
    const float w = top_w[b * 2 + k];
    int pos = 0;
#pragma unroll
    for (int ex = 0; ex < NEXP; ex++) {
      unsigned long long m = __ballot(e == ex);
      if (e == ex) {
        int nset = __popcll(m);
        int rank = __popcll(m & ((1ull << lane) - 1ull));
        int leader = __ffsll((long long)m) - 1;
        int base = 0;
        if (lane == leader) base = atomicAdd(&cursor[ex], nset);
        base = __shfl(base, leader);
        pos = off_p[ex] + base + rank;
      }
    }
    rows16k[pos] = b;
    wgt[pos] = w;
    slot_of[b * 2 + k] = pos;
  }
}

// ---------------- 256x256 BK=64 4-phase counted-vmcnt grouped GEMM ----------------
// 512 threads = 8 waves as 2(M)x4(N); per-wave output 128x64.
// Double-buffered LDS (128 KiB). Tile t's 8 global_load_lds are issued quarter-wise
// inside iter t-1's four phases -> a full iteration of prefetch depth. The only vmem
// wait is a counted vmcnt(2) at phase 0 (next tile's first quarter stays in flight);
// raw s_barrier per phase; setprio(1) around each 16-MFMA cluster (T5).
// XOR chunk swizzle (chunk ^= row&7) pre-applied on global source, applied on ds_read.
template<bool GATHER, bool GELU>
__global__ __launch_bounds__(512, 2) void gemm256_kernel(
    const uint16_t* __restrict__ Abase, const uint16_t* __restrict__ Wb,
    const float* __restrict__ bias, const int* __restrict__ rows16k,
    const int* __restrict__ counts, const int* __restrict__ off_p,
    const float* __restrict__ zeropad, uint16_t* __restrict__ outb,
    int Nfull, int Kdim) {
  const int e = blockIdx.z;
  const int ne = counts[e];
  const int rb = blockIdx.y;
  if (rb * 256 >= ne) return;
  const int nbase = blockIdx.x * 256;
  const int sbase = off_p[e] + rb * 256;
  const int nt = Kdim / 64;

  __shared__ __align__(16) uint16_t smem[2 * 2 * 256 * 64];  // 128 KiB

  const int tid = threadIdx.x;
  const int lane = tid & 63;
  const int wid = tid >> 6;
  const int wm = wid >> 2, wn = wid & 3;
  const int lr = lane & 15, lh = lane >> 4;
  const int swz8 = (((tid & 7) ^ ((tid >> 3) & 7)) * 8);

  const uint16_t* srcA[4]; int stA[4];
  const uint16_t* srcB[4];
#pragma unroll
  for (int is = 0; is < 4; is++) {
    const int r = (tid >> 3) + is * 64;
    if (GATHER) {
      int tok = rows16k[sbase + r];
      srcA[is] = (tok >= 0) ? (Abase + (size_t)tok * Kdim + swz8) : (const uint16_t*)zeropad;
      stA[is] = (tok >= 0) ? 64 : 0;
    } else {
      srcA[is] = Abase + (size_t)(sbase + r) * Kdim + swz8;
      stA[is] = 64;
    }
    srcB[is] = Wb + ((size_t)e * Nfull + nbase + r) * Kdim + swz8;
  }

  f32x4 acc[8][4];
#pragma unroll
  for (int mi = 0; mi < 8; mi++)
#pragma unroll
    for (int ni = 0; ni < 4; ni++) acc[mi][ni] = (f32x4){0.f, 0.f, 0.f, 0.f};

  // prologue: tile 0, all 4 quarters (8 loads)
#pragma unroll
  for (int q = 0; q < 4; q++) {
    uint16_t* dA = &smem[0];
    uint16_t* dB = dA + 16384;
    load_lds16(srcA[q], dA + (q * 512 + tid) * 8);
    load_lds16(srcB[q], dB + (q * 512 + tid) * 8);
    srcA[q] += stA[q]; srcB[q] += 64;
  }

  for (int t = 0; t < nt; ++t) {
    const int cur = t & 1;
    const bool pf = (t + 1 < nt);
    const uint16_t* sA = &smem[cur * 32768];
    const uint16_t* sB = sA + 16384;
    uint16_t* dA = &smem[(cur ^ 1) * 32768];
    uint16_t* dB = dA + 16384;

    bf16x8 bfr[2][4];
#pragma unroll
    for (int p = 0; p < 4; ++p) {
      // issue quarter p of tile t+1 (2 loads) into the other buffer
      if (pf) {
        load_lds16(srcA[p], dA + (p * 512 + tid) * 8);
        load_lds16(srcB[p], dB + (p * 512 + tid) * 8);
        srcA[p] += stA[p]; srcB[p] += 64;
      }
      if (p == 0) {
        if (pf) asm volatile("s_waitcnt vmcnt(2)" ::: "memory");   // tile t landed; q0 of t+1 in flight
        else    asm volatile("s_waitcnt vmcnt(0)" ::: "memory");   // last tile (issued a full iter ago)
        __builtin_amdgcn_s_barrier();
        // B fragments for the whole K-tile (persist across phases)
#pragma unroll
        for (int kk = 0; kk < 2; kk++)
#pragma unroll
          for (int ni = 0; ni < 4; ni++) {
            const int row = wn * 64 + ni * 16 + lr;
            const int c = (kk * 4 + lh) ^ (lr & 7);
            bfr[kk][ni] = *(const bf16x8*)&sB[row * 64 + c * 8];
          }
      }
      // A fragments for this phase: mi = 2p, 2p+1
      bf16x8 afr[2][2];
#pragma unroll
      for (int kk = 0; kk < 2; kk++)
#pragma unroll
        for (int m2 = 0; m2 < 2; m2++) {
          const int row = wm * 128 + (2 * p + m2) * 16 + lr;
          const int c = (kk * 4 + lh) ^ (lr & 7);
          afr[kk][m2] = *(const bf16x8*)&sA[row * 64 + c * 8];
        }
      __builtin_amdgcn_s_setprio(1);
#pragma unroll
      for (int kk = 0; kk < 2; kk++)
#pragma unroll
        for (int m2 = 0; m2 < 2; m2++)
#pragma unroll
          for (int ni = 0; ni < 4; ni++)
            acc[2 * p + m2][ni] = __builtin_amdgcn_mfma_f32_16x16x32_bf16(
                afr[kk][m2], bfr[kk][ni], acc[2 * p + m2][ni], 0, 0, 0);
      __builtin_amdgcn_s_setprio(0);
      __builtin_amdgcn_s_barrier();
    }
  }

  float biasv[4];
#pragma unroll
  for (int ni = 0; ni < 4; ni++)
    biasv[ni] = bias[(size_t)e * Nfull + nbase + wn * 64 + ni * 16 + lr];
#pragma unroll
  for (int mi = 0; mi < 8; mi++)
#pragma unroll
    for (int ni = 0; ni < 4; ni++)
#pragma unroll
      for (int r = 0; r < 4; r++) {
        const int row = wm * 128 + mi * 16 + lh * 4 + r;
        const int col = nbase + wn * 64 + ni * 16 + lr;
        float t = acc[mi][ni][r] + biasv[ni];
        float g;
        if (GELU) {
          // tanh-form GELU via exp2: g = t - t/(2^(t*(c1 + c2*t^2)) + 1)
          float t2 = t * t;
          float v = t * fmaf(0.1029437f, t2, 2.3022085f);
          float ex = exp2f(v);
          float rr = 1.0f / (ex + 1.0f);
          g = t - t * rr;
        } else {
          g = t;
        }
        outb[(size_t)(sbase + row) * Nfull + col] = f2b(g);
      }
}

// ---------------- combine: out[b] = w0*y[slot0] + w1*y[slot1] ----------------
__global__ void combine_kernel(const uint16_t* __restrict__ y, const int* __restrict__ slot_of,
                               const float* __restrict__ top_w, float* __restrict__ out) {
  const int b = blockIdx.x;
  const int t = threadIdx.x;
  const int s0 = slot_of[b * 2], s1 = slot_of[b * 2 + 1];
  const float w0 = top_w[b * 2], w1 = top_w[b * 2 + 1];
  uint64_t p0 = *(const uint64_t*)(y + (size_t)s0 * DIM + t * 4);
  uint64_t p1 = *(const uint64_t*)(y + (size_t)s1 * DIM + t * 4);
  float4 r;
  r.x = w0 * b2f((uint32_t)(p0 >> 0) & 0xFFFFu)  + w1 * b2f((uint32_t)(p1 >> 0) & 0xFFFFu);
  r.y = w0 * b2f((uint32_t)(p0 >> 16) & 0xFFFFu) + w1 * b2f((uint32_t)(p1 >> 16) & 0xFFFFu);
  r.z = w0 * b2f((uint32_t)(p0 >> 32) & 0xFFFFu) + w1 * b2f((uint32_t)(p1 >> 32) & 0xFFFFu);
  r.w = w0 * b2f((uint32_t)(p0 >> 48) & 0xFFFFu) + w1 * b2f((uint32_t)(p1 >> 48) & 0xFFFFu);
  *(float4*)(out + (size_t)b * DIM + t * 4) = r;
}

// ---------------- launch ----------------
extern "C" void kernel_launch(void* const* d_in, const int* in_sizes, int n_in,
                              void* d_out, int out_size, void* d_ws, size_t ws_size,
                              hipStream_t stream) {
  const float* x  = (const float*)d_in[0];
  const float* Wr = (const float*)d_in[1];
  const float* br = (const float*)d_in[2];
  const float* W1 = (const float*)d_in[3];
  const float* b1 = (const float*)d_in[4];
  const float* W2 = (const float*)d_in[5];
  const float* b2 = (const float*)d_in[6];
  float* out = (float*)d_out;

  char* ws = (char*)d_ws;
  uint16_t* W1b = (uint16_t*)ws; ws += (size_t)NEXP * HID * DIM * 2;   // 64 MB
  uint16_t* W2b = (uint16_t*)ws; ws += (size_t)NEXP * DIM * HID * 2;   // 64 MB
  uint16_t* xb  = (uint16_t*)ws; ws += (size_t)B_TOK * DIM * 2;        // 16 MB
  uint16_t* h   = (uint16_t*)ws; ws += (size_t)MAXSLOT * HID * 2;      // 151 MB
  uint16_t* yb  = (uint16_t*)ws; ws += (size_t)MAXSLOT * DIM * 2;      // 38 MB
  int*   top_i  = (int*)ws;   ws += (size_t)B_TOK * 2 * 4;
  float* top_w  = (float*)ws; ws += (size_t)B_TOK * 2 * 4;
  int*   slot_of= (int*)ws;   ws += (size_t)B_TOK * 2 * 4;
  int*   rows16k= (int*)ws;   ws += (size_t)MAXSLOT * 4;
  float* wgt    = (float*)ws; ws += (size_t)MAXSLOT * 4;
  int*   counts = (int*)ws;   ws += 64;
  int*   cursor = (int*)ws;   ws += 64;
  int*   off_p  = (int*)ws;   ws += 64;
  float* zeropad= (float*)ws; ws += 64;

  init_kernel<<<dim3((MAXSLOT + 255) / 256), dim3(256), 0, stream>>>(rows16k, counts, cursor, zeropad);
  transpose_cvt_kernel<<<dim3(HID / 32, DIM / 32, NEXP), dim3(32, 8), 0, stream>>>(W1, W1b, DIM, HID);
  transpose_cvt_kernel<<<dim3(DIM / 32, HID / 32, NEXP), dim3(32, 8), 0, stream>>>(W2, W2b, HID, DIM);
  router_kernel<<<dim3(B_TOK / 4), dim3(256), 0, stream>>>(x, Wr, br, top_i, top_w, counts, xb);
  offsets_kernel<<<dim3(1), dim3(1), 0, stream>>>(counts, off_p);
  scatter_kernel<<<dim3(B_TOK / 256), dim3(256), 0, stream>>>(top_i, top_w, off_p, cursor, rows16k, wgt, slot_of);
  // gemm1: h = gelu(gather(x) @ W1^T + b1)   [M=slots, N=HID, K=DIM]
  gemm256_kernel<true, true><<<dim3(HID / 256, 32, NEXP), dim3(512), 0, stream>>>(
      xb, W1b, b1, rows16k, counts, off_p, zeropad, h, HID, DIM);
  // gemm2: y = h @ W2^T + b2                  [M=slots, N=DIM, K=HID]
  gemm256_kernel<false, false><<<dim3(DIM / 256, 32, NEXP), dim3(512), 0, stream>>>(
      h, W2b, b2, rows16k, counts, off_p, zeropad, yb, DIM, HID);
  combine_kernel<<<dim3(B_TOK), dim3(256), 0, stream>>>(yb, slot_of, top_w, out);
}

// Round 7
// 739.935 us; speedup vs baseline: 1.9305x; 1.0607x over previous
//
#include <hip/hip_runtime.h>
#include <hip/hip_bf16.h>
#include <cstdint>
#include <cstddef>

#define B_TOK 8192
#define DIM   1024
#define HID   4096
#define NEXP  8
#define MAXSLOT 17408  // B_TOK*2 + NEXP*127 padding (128-aligned expert offsets)

typedef __bf16 bf16x8 __attribute__((ext_vector_type(8)));
typedef float  f32x4  __attribute__((ext_vector_type(4)));

__device__ __forceinline__ void load_lds16(const void* g, void* l) {
  __builtin_amdgcn_global_load_lds(
      (const __attribute__((address_space(1))) void*)g,
      (__attribute__((address_space(3))) void*)l, 16, 0, 0);
}

// fp32 -> bf16 RNE
__device__ __forceinline__ uint16_t f2b(float f) {
  uint32_t u = __builtin_bit_cast(uint32_t, f);
  return (uint16_t)((u + 0x7FFFu + ((u >> 16) & 1u)) >> 16);
}
__device__ __forceinline__ float b2f(uint32_t hbits) {
  uint32_t u = hbits << 16;
  return __builtin_bit_cast(float, u);
}

// ---------------- init ----------------
__global__ void init_kernel(int* __restrict__ rows16k, int* __restrict__ counts,
                            int* __restrict__ cursor, float* __restrict__ zeropad) {
  int i = blockIdx.x * 256 + threadIdx.x;
  if (i < MAXSLOT) rows16k[i] = -1;
  if (i < NEXP) { counts[i] = 0; cursor[i] = 0; }
  if (i < 16) zeropad[i] = 0.f;
}

// out[n][m] = bf16(in[m][n]); per-expert slab. grid(N/32, M/32, E), block(32,8)
__global__ void transpose_cvt_kernel(const float* __restrict__ in, uint16_t* __restrict__ out,
                                     int M, int N) {
  __shared__ float tile[32][33];
  const size_t base = (size_t)blockIdx.z * M * N;
  const int x0 = blockIdx.x * 32, y0 = blockIdx.y * 32;
  const int tx = threadIdx.x, ty = threadIdx.y;
#pragma unroll
  for (int i = 0; i < 4; i++)
    tile[ty + i * 8][tx] = in[base + (size_t)(y0 + ty + i * 8) * N + x0 + tx];
  __syncthreads();
  const int tl = ty * 32 + tx;
  const int r = tl >> 3, c4 = (tl & 7) * 4;
  uint64_t p = (uint64_t)f2b(tile[c4 + 0][r]) | ((uint64_t)f2b(tile[c4 + 1][r]) << 16) |
               ((uint64_t)f2b(tile[c4 + 2][r]) << 32) | ((uint64_t)f2b(tile[c4 + 3][r]) << 48);
  *(uint64_t*)(out + base + (size_t)(x0 + r) * M + y0 + c4) = p;
}

// ---------------- router (+ x -> bf16 conversion fused) ----------------
__global__ void router_kernel(const float* __restrict__ x, const float* __restrict__ Wr,
                              const float* __restrict__ br, int* __restrict__ top_i,
                              float* __restrict__ top_w, int* __restrict__ counts,
                              uint16_t* __restrict__ xb) {
  const int wave = threadIdx.x >> 6, lane = threadIdx.x & 63;
  const int b = blockIdx.x * 4 + wave;
  float acc[NEXP];
#pragma unroll
  for (int e = 0; e < NEXP; e++) acc[e] = 0.f;
  const float* xr = x + (size_t)b * DIM;
  uint16_t* xbr = xb + (size_t)b * DIM;
  for (int d = lane; d < DIM; d += 64) {
    float xv = xr[d];
    xbr[d] = f2b(xv);
    const float4* wr = (const float4*)(Wr + (size_t)d * NEXP);
    float4 w0 = wr[0], w1 = wr[1];
    acc[0] += xv * w0.x; acc[1] += xv * w0.y; acc[2] += xv * w0.z; acc[3] += xv * w0.w;
    acc[4] += xv * w1.x; acc[5] += xv * w1.y; acc[6] += xv * w1.z; acc[7] += xv * w1.w;
  }
#pragma unroll
  for (int e = 0; e < NEXP; e++)
#pragma unroll
    for (int off = 32; off; off >>= 1) acc[e] += __shfl_xor(acc[e], off);
  if (lane == 0) {
    float l[NEXP];
#pragma unroll
    for (int e = 0; e < NEXP; e++) l[e] = acc[e] + br[e];
    int i0 = 0; float v0 = l[0];
#pragma unroll
    for (int e = 1; e < NEXP; e++) if (l[e] > v0) { v0 = l[e]; i0 = e; }
    int i1 = -1; float v1 = -3.4e38f;
#pragma unroll
    for (int e = 0; e < NEXP; e++) if (e != i0 && l[e] > v1) { v1 = l[e]; i1 = e; }
    float w0 = 1.f / (1.f + expf(v1 - v0));
    float w1 = 1.f - w0;
    top_i[b * 2 + 0] = i0; top_i[b * 2 + 1] = i1;
    top_w[b * 2 + 0] = w0; top_w[b * 2 + 1] = w1;
    atomicAdd(&counts[i0], 1);
    atomicAdd(&counts[i1], 1);
  }
}

__global__ void offsets_kernel(const int* __restrict__ counts, int* __restrict__ off_p) {
  int o = 0;
  for (int e = 0; e < NEXP; e++) { off_p[e] = o; o += (counts[e] + 127) & ~127; }
  off_p[NEXP] = o;
}

// wave-aggregated scatter: 8 atomics per wave per k instead of 64
__global__ void scatter_kernel(const int* __restrict__ top_i, const float* __restrict__ top_w,
                               const int* __restrict__ off_p, int* __restrict__ cursor,
                               int* __restrict__ rows16k, float* __restrict__ wgt,
                               int* __restrict__ slot_of) {
  const int b = blockIdx.x * 256 + threadIdx.x;
  const int lane = threadIdx.x & 63;
#pragma unroll
  for (int k = 0; k < 2; k++) {
    const int e = top_i[b * 2 + k];
    const float w = top_w[b * 2 + k];
    int pos = 0;
#pragma unroll
    for (int ex = 0; ex < NEXP; ex++) {
      unsigned long long m = __ballot(e == ex);
      if (e == ex) {
        int nset = __popcll(m);
        int rank = __popcll(m & ((1ull << lane) - 1ull));
        int leader = __ffsll((long long)m) - 1;
        int base = 0;
        if (lane == leader) base = atomicAdd(&cursor[ex], nset);
        base = __shfl(base, leader);
        pos = off_p[ex] + base + rank;
      }
    }
    rows16k[pos] = b;
    wgt[pos] = w;
    slot_of[b * 2 + k] = pos;
  }
}

// ---------------- 128x128 BK=64 2-phase dbuf grouped GEMM, 2 blocks/CU ----------------
// 256 threads = 4 waves as 2(M)x2(N); per-wave output 64x64.
// LDS 64 KiB (2 buf x (A 128x64 + B 128x64)); per K-step: STAGE(next) -> COMPUTE(cur)
// -> __syncthreads(). Cross-BLOCK overlap (2 blocks/CU) hides the stage drain.
// XOR chunk swizzle (chunk ^= row&7) pre-applied on global source, applied on ds_read.
template<bool GATHER, bool GELU>
__global__ __launch_bounds__(256, 2) void gemm128_kernel(
    const uint16_t* __restrict__ Abase, const uint16_t* __restrict__ Wb,
    const float* __restrict__ bias, const int* __restrict__ rows16k,
    const int* __restrict__ counts, const int* __restrict__ off_p,
    const float* __restrict__ zeropad, uint16_t* __restrict__ outb,
    int Nfull, int Kdim) {
  const int e = blockIdx.z;
  const int ne = counts[e];
  const int rb = blockIdx.y;
  if (rb * 128 >= ne) return;
  const int nbase = blockIdx.x * 128;
  const int sbase = off_p[e] + rb * 128;
  const int nt = Kdim / 64;

  __shared__ __align__(16) uint16_t smem[2 * 2 * 128 * 64];  // 64 KiB

  const int tid = threadIdx.x;
  const int lane = tid & 63;
  const int wid = tid >> 6;
  const int wm = wid >> 1, wn = wid & 1;
  const int lr = lane & 15, lh = lane >> 4;
  const int swz8 = (((tid & 7) ^ ((tid >> 3) & 7)) * 8);

  const uint16_t* srcA[4]; int stA[4];
  const uint16_t* srcB[4];
#pragma unroll
  for (int is = 0; is < 4; is++) {
    const int r = (tid >> 3) + is * 32;
    if (GATHER) {
      int tok = rows16k[sbase + r];
      srcA[is] = (tok >= 0) ? (Abase + (size_t)tok * Kdim + swz8) : (const uint16_t*)zeropad;
      stA[is] = (tok >= 0) ? 64 : 0;
    } else {
      srcA[is] = Abase + (size_t)(sbase + r) * Kdim + swz8;
      stA[is] = 64;
    }
    srcB[is] = Wb + ((size_t)e * Nfull + nbase + r) * Kdim + swz8;
  }

  f32x4 acc[4][4];
#pragma unroll
  for (int mi = 0; mi < 4; mi++)
#pragma unroll
    for (int ni = 0; ni < 4; ni++) acc[mi][ni] = (f32x4){0.f, 0.f, 0.f, 0.f};

  auto STAGE = [&](int buf) {
    uint16_t* dA = &smem[buf * 16384];
    uint16_t* dB = dA + 8192;
#pragma unroll
    for (int is = 0; is < 4; is++) {
      load_lds16(srcA[is], dA + (is * 256 + tid) * 8);
      load_lds16(srcB[is], dB + (is * 256 + tid) * 8);
      srcA[is] += stA[is]; srcB[is] += 64;
    }
  };

  auto COMPUTE = [&](int buf) {
    const uint16_t* sA = &smem[buf * 16384];
    const uint16_t* sB = sA + 8192;
#pragma unroll
    for (int kk = 0; kk < 2; kk++) {
      bf16x8 afr[4], bfr[4];
#pragma unroll
      for (int ni = 0; ni < 4; ni++) {
        const int row = wn * 64 + ni * 16 + lr;
        const int c = (kk * 4 + lh) ^ (lr & 7);
        bfr[ni] = *(const bf16x8*)&sB[row * 64 + c * 8];
      }
#pragma unroll
      for (int mi = 0; mi < 4; mi++) {
        const int row = wm * 64 + mi * 16 + lr;
        const int c = (kk * 4 + lh) ^ (lr & 7);
        afr[mi] = *(const bf16x8*)&sA[row * 64 + c * 8];
      }
#pragma unroll
      for (int mi = 0; mi < 4; mi++)
#pragma unroll
        for (int ni = 0; ni < 4; ni++)
          acc[mi][ni] = __builtin_amdgcn_mfma_f32_16x16x32_bf16(afr[mi], bfr[ni], acc[mi][ni], 0, 0, 0);
    }
  };

  STAGE(0);
  __syncthreads();                 // prologue drain only
  for (int t = 0; t < nt - 1; ++t) {
    STAGE((t & 1) ^ 1);            // issue next tile FIRST
    COMPUTE(t & 1);                // MFMA hides the prefetch latency
    __syncthreads();               // single drain+barrier per K-step
  }
  COMPUTE((nt - 1) & 1);

  float biasv[4];
#pragma unroll
  for (int ni = 0; ni < 4; ni++)
    biasv[ni] = bias[(size_t)e * Nfull + nbase + wn * 64 + ni * 16 + lr];
#pragma unroll
  for (int mi = 0; mi < 4; mi++)
#pragma unroll
    for (int ni = 0; ni < 4; ni++)
#pragma unroll
      for (int r = 0; r < 4; r++) {
        const int row = wm * 64 + mi * 16 + lh * 4 + r;
        const int col = nbase + wn * 64 + ni * 16 + lr;
        float t = acc[mi][ni][r] + biasv[ni];
        float g;
        if (GELU) {
          // tanh-form GELU via exp2: g = t - t/(2^(t*(c1 + c2*t^2)) + 1)
          float t2 = t * t;
          float v = t * fmaf(0.1029437f, t2, 2.3022085f);
          float ex = exp2f(v);
          float rr = 1.0f / (ex + 1.0f);
          g = t - t * rr;
        } else {
          g = t;
        }
        outb[(size_t)(sbase + row) * Nfull + col] = f2b(g);
      }
}

// ---------------- combine: out[b] = w0*y[slot0] + w1*y[slot1] ----------------
__global__ void combine_kernel(const uint16_t* __restrict__ y, const int* __restrict__ slot_of,
                               const float* __restrict__ top_w, float* __restrict__ out) {
  const int b = blockIdx.x;
  const int t = threadIdx.x;
  const int s0 = slot_of[b * 2], s1 = slot_of[b * 2 + 1];
  const float w0 = top_w[b * 2], w1 = top_w[b * 2 + 1];
  uint64_t p0 = *(const uint64_t*)(y + (size_t)s0 * DIM + t * 4);
  uint64_t p1 = *(const uint64_t*)(y + (size_t)s1 * DIM + t * 4);
  float4 r;
  r.x = w0 * b2f((uint32_t)(p0 >> 0) & 0xFFFFu)  + w1 * b2f((uint32_t)(p1 >> 0) & 0xFFFFu);
  r.y = w0 * b2f((uint32_t)(p0 >> 16) & 0xFFFFu) + w1 * b2f((uint32_t)(p1 >> 16) & 0xFFFFu);
  r.z = w0 * b2f((uint32_t)(p0 >> 32) & 0xFFFFu) + w1 * b2f((uint32_t)(p1 >> 32) & 0xFFFFu);
  r.w = w0 * b2f((uint32_t)(p0 >> 48) & 0xFFFFu) + w1 * b2f((uint32_t)(p1 >> 48) & 0xFFFFu);
  *(float4*)(out + (size_t)b * DIM + t * 4) = r;
}

// ---------------- launch ----------------
extern "C" void kernel_launch(void* const* d_in, const int* in_sizes, int n_in,
                              void* d_out, int out_size, void* d_ws, size_t ws_size,
                              hipStream_t stream) {
  const float* x  = (const float*)d_in[0];
  const float* Wr = (const float*)d_in[1];
  const float* br = (const float*)d_in[2];
  const float* W1 = (const float*)d_in[3];
  const float* b1 = (const float*)d_in[4];
  const float* W2 = (const float*)d_in[5];
  const float* b2 = (const float*)d_in[6];
  float* out = (float*)d_out;

  char* ws = (char*)d_ws;
  uint16_t* W1b = (uint16_t*)ws; ws += (size_t)NEXP * HID * DIM * 2;   // 64 MB
  uint16_t* W2b = (uint16_t*)ws; ws += (size_t)NEXP * DIM * HID * 2;   // 64 MB
  uint16_t* xb  = (uint16_t*)ws; ws += (size_t)B_TOK * DIM * 2;        // 16 MB
  uint16_t* h   = (uint16_t*)ws; ws += (size_t)MAXSLOT * HID * 2;      // 143 MB
  uint16_t* yb  = (uint16_t*)ws; ws += (size_t)MAXSLOT * DIM * 2;      // 36 MB
  int*   top_i  = (int*)ws;   ws += (size_t)B_TOK * 2 * 4;
  float* top_w  = (float*)ws; ws += (size_t)B_TOK * 2 * 4;
  int*   slot_of= (int*)ws;   ws += (size_t)B_TOK * 2 * 4;
  int*   rows16k= (int*)ws;   ws += (size_t)MAXSLOT * 4;
  float* wgt    = (float*)ws; ws += (size_t)MAXSLOT * 4;
  int*   counts = (int*)ws;   ws += 64;
  int*   cursor = (int*)ws;   ws += 64;
  int*   off_p  = (int*)ws;   ws += 64;
  float* zeropad= (float*)ws; ws += 64;

  init_kernel<<<dim3((MAXSLOT + 255) / 256), dim3(256), 0, stream>>>(rows16k, counts, cursor, zeropad);
  transpose_cvt_kernel<<<dim3(HID / 32, DIM / 32, NEXP), dim3(32, 8), 0, stream>>>(W1, W1b, DIM, HID);
  transpose_cvt_kernel<<<dim3(DIM / 32, HID / 32, NEXP), dim3(32, 8), 0, stream>>>(W2, W2b, HID, DIM);
  router_kernel<<<dim3(B_TOK / 4), dim3(256), 0, stream>>>(x, Wr, br, top_i, top_w, counts, xb);
  offsets_kernel<<<dim3(1), dim3(1), 0, stream>>>(counts, off_p);
  scatter_kernel<<<dim3(B_TOK / 256), dim3(256), 0, stream>>>(top_i, top_w, off_p, cursor, rows16k, wgt, slot_of);
  // gemm1: h = gelu(gather(x) @ W1^T + b1)   [M=slots, N=HID, K=DIM]
  gemm128_kernel<true, true><<<dim3(HID / 128, 64, NEXP), dim3(256), 0, stream>>>(
      xb, W1b, b1, rows16k, counts, off_p, zeropad, h, HID, DIM);
  // gemm2: y = h @ W2^T + b2                  [M=slots, N=DIM, K=HID]
  gemm128_kernel<false, false><<<dim3(DIM / 128, 64, NEXP), dim3(256), 0, stream>>>(
      h, W2b, b2, rows16k, counts, off_p, zeropad, yb, DIM, HID);
  combine_kernel<<<dim3(B_TOK), dim3(256), 0, stream>>>(yb, slot_of, top_w, out);
}